// Round 12
// baseline (21.437 us; speedup 1.0000x reference)
//
#include <hip/hip_runtime.h>
#include <math.h>

// B=4096, O=8, E=64, I=4, V=3, P=perm(8,3)=336
// unary_feats  (B,8,64)   f32
// binary_feats (B,8,8,64) f32
// rule_unary   (4,3,64)   f32  = [12][64]
// rule_binary  (4,3,3,64) f32  = [36][64]  (rule = i*9 + n*3 + m)
// out          (B,4)      f32  (col0=sel0+sel1, col1=sel2+sel3, col2=col3=0)
//
// v12 = v11 (wave-autonomous, 2 elem/wave, zero barriers, single dispatch)
// with phase 2 deleted algebraically:
//   q_t[x][y] = dot(bf[x,y], rb_fwd) + dot(bf[y,x], rb_rev)
// computed as TWO GEMMs over the same A (64 pos x 12 cols, K=64):
//   G1 = A*B_fwd (C kept in registers), G2 = A*B_rev (stored to LDS),
//   combine: q[c][p] = g1[c][p] + q2[c][rev(p)]   (rev(p) = bit-swap)
// Separable terms s_n[v] = dot(uf[v],ru_n) + dot(bf[v,v],rb_nn) via one
// 4-MFMA accumulated GEMM (diag rows re-read from global: L1-hot).
// Phase 3 adds s-terms: score = q01[a][b]+q02[a][c]+q12[b][c]+s0[a]+s1[b]+s2[c].

typedef __attribute__((ext_vector_type(8))) __bf16 bf16x8;
typedef __attribute__((ext_vector_type(4))) float  f32x4;

#define QS 68   // q/q2 row stride (floats)
#define SS 12   // s row stride

__device__ inline bf16x8 cvt2(const float4 v0, const float4 v1) {
    bf16x8 r;
    r[0] = (__bf16)v0.x; r[1] = (__bf16)v0.y; r[2] = (__bf16)v0.z; r[3] = (__bf16)v0.w;
    r[4] = (__bf16)v1.x; r[5] = (__bf16)v1.y; r[6] = (__bf16)v1.z; r[7] = (__bf16)v1.w;
    return r;
}

__global__ __launch_bounds__(64, 2) void rule_learner_kernel(
    const float* __restrict__ uf,    // (B,8,64)
    const float* __restrict__ bfe,   // (B,8,8,64)
    const float* __restrict__ ru,    // [12][64]
    const float* __restrict__ rb,    // [36][64]
    float* __restrict__ out)         // (B,4)
{
    const int b0    = blockIdx.x * 2;
    const int lane  = threadIdx.x;   // one wave per block
    const int row16 = lane & 15;
    const int kg    = lane >> 4;
    const int kb    = kg * 8;

    __shared__ float q_s [12 * QS];  // 3264 B  combined [col=i*3+t][pair]
    __shared__ float q2_s[12 * QS];  // 3264 B  G2 raw   [col][pair]
    __shared__ float ss_s[12 * SS];  // 576 B   separable [col=i*3+n][v]

    // ---- rule B-fragments, packed in-wave once (L1-hot f32) ----
    // B-frag for 16x16x32: col = lane&15, k = kg*8 + j
    const int cc16  = row16 < 12 ? row16 : 11;      // clamped col
    const int ii    = cc16 / 3, tt = cc16 - ii * 3;
    const int rule1 = ii * 9 + (tt == 0 ? 1 : tt == 1 ? 2 : 5);  // (0,1)(0,2)(1,2)
    const int rule2 = ii * 9 + (tt == 0 ? 3 : tt == 1 ? 6 : 7);  // (1,0)(2,0)(2,1)
    const int ruled = ii * 9 + tt * 4;                            // (n,n)
    bf16x8 b1f0, b1f1, b2f0, b2f1, dbf0, dbf1, ruf0, ruf1;
    {
        const float* r1 = rb + rule1 * 64 + kb;
        b1f0 = cvt2(*(const float4*)r1,        *(const float4*)(r1 + 4));
        b1f1 = cvt2(*(const float4*)(r1 + 32), *(const float4*)(r1 + 36));
        const float* r2 = rb + rule2 * 64 + kb;
        b2f0 = cvt2(*(const float4*)r2,        *(const float4*)(r2 + 4));
        b2f1 = cvt2(*(const float4*)(r2 + 32), *(const float4*)(r2 + 36));
        const float* rd = rb + ruled * 64 + kb;
        dbf0 = cvt2(*(const float4*)rd,        *(const float4*)(rd + 4));
        dbf1 = cvt2(*(const float4*)(rd + 32), *(const float4*)(rd + 36));
        const float* rr = ru + cc16 * 64 + kb;
        ruf0 = cvt2(*(const float4*)rr,        *(const float4*)(rr + 4));
        ruf1 = cvt2(*(const float4*)(rr + 32), *(const float4*)(rr + 36));
    }

    // ---- elem0 feature loads ----
    float4 af[4][4], uA[4], dA[4];
    {
        const float* base = bfe + (size_t)b0 * 4096;
        #pragma unroll
        for (int t = 0; t < 4; ++t) {
            const float* rp = base + (size_t)(t * 16 + row16) * 64 + kb;
            af[t][0] = *(const float4*)rp;
            af[t][1] = *(const float4*)(rp + 4);
            af[t][2] = *(const float4*)(rp + 32);
            af[t][3] = *(const float4*)(rp + 36);
        }
        const int v8c = row16 < 8 ? row16 : 7;
        const float* up = uf + (size_t)b0 * 512 + v8c * 64 + kb;
        uA[0] = *(const float4*)up;        uA[1] = *(const float4*)(up + 4);
        uA[2] = *(const float4*)(up + 32); uA[3] = *(const float4*)(up + 36);
        const float* dp = base + v8c * 576 + kb;   // bf[v][v], L1-hot
        dA[0] = *(const float4*)dp;        dA[1] = *(const float4*)(dp + 4);
        dA[2] = *(const float4*)(dp + 32); dA[3] = *(const float4*)(dp + 36);
    }

    #pragma unroll
    for (int e = 0; e < 2; ++e) {
        // ---- phase 1: G1 (regs) / G2 (LDS) / separable (LDS) ----
        f32x4 g1[4];
        #pragma unroll
        for (int t = 0; t < 4; ++t) {
            const bf16x8 a0 = cvt2(af[t][0], af[t][1]);   // k 0..31 slice
            const bf16x8 a1 = cvt2(af[t][2], af[t][3]);   // k 32..63
            f32x4 z1 = {0.f, 0.f, 0.f, 0.f};
            z1 = __builtin_amdgcn_mfma_f32_16x16x32_bf16(a0, b1f0, z1, 0, 0, 0);
            z1 = __builtin_amdgcn_mfma_f32_16x16x32_bf16(a1, b1f1, z1, 0, 0, 0);
            g1[t] = z1;
            f32x4 z2 = {0.f, 0.f, 0.f, 0.f};
            z2 = __builtin_amdgcn_mfma_f32_16x16x32_bf16(a0, b2f0, z2, 0, 0, 0);
            z2 = __builtin_amdgcn_mfma_f32_16x16x32_bf16(a1, b2f1, z2, 0, 0, 0);
            // C: col = lane&15, rows(pairs) = t*16 + kg*4 + r
            if (row16 < 12)
                *(float4*)&q2_s[row16 * QS + t * 16 + kg * 4] = *(float4*)&z2;
        }
        {
            const bf16x8 ua0 = cvt2(uA[0], uA[1]);
            const bf16x8 ua1 = cvt2(uA[2], uA[3]);
            const bf16x8 da0 = cvt2(dA[0], dA[1]);
            const bf16x8 da1 = cvt2(dA[2], dA[3]);
            f32x4 zs = {0.f, 0.f, 0.f, 0.f};
            zs = __builtin_amdgcn_mfma_f32_16x16x32_bf16(ua0, ruf0, zs, 0, 0, 0);
            zs = __builtin_amdgcn_mfma_f32_16x16x32_bf16(ua1, ruf1, zs, 0, 0, 0);
            zs = __builtin_amdgcn_mfma_f32_16x16x32_bf16(da0, dbf0, zs, 0, 0, 0);
            zs = __builtin_amdgcn_mfma_f32_16x16x32_bf16(da1, dbf1, zs, 0, 0, 0);
            if (row16 < 12 && kg < 2)     // valid objects v = kg*4+r < 8
                *(float4*)&ss_s[row16 * SS + kg * 4] = *(float4*)&zs;
        }

        // ---- issue elem1 loads NOW (latency hides under combine+phase3) ----
        if (e == 0) {
            const float* base = bfe + (size_t)(b0 + 1) * 4096;
            #pragma unroll
            for (int t = 0; t < 4; ++t) {
                const float* rp = base + (size_t)(t * 16 + row16) * 64 + kb;
                af[t][0] = *(const float4*)rp;
                af[t][1] = *(const float4*)(rp + 4);
                af[t][2] = *(const float4*)(rp + 32);
                af[t][3] = *(const float4*)(rp + 36);
            }
            const int v8c = row16 < 8 ? row16 : 7;
            const float* up = uf + (size_t)(b0 + 1) * 512 + v8c * 64 + kb;
            uA[0] = *(const float4*)up;        uA[1] = *(const float4*)(up + 4);
            uA[2] = *(const float4*)(up + 32); uA[3] = *(const float4*)(up + 36);
            const float* dp = base + v8c * 576 + kb;
            dA[0] = *(const float4*)dp;        dA[1] = *(const float4*)(dp + 4);
            dA[2] = *(const float4*)(dp + 32); dA[3] = *(const float4*)(dp + 36);
        }

        // ---- combine: q[c][p] = g1[c][p] + q2[c][rev(p)]  (in-wave DS order:
        // q2 writes above precede these reads in program order) ----
        if (row16 < 12) {
            #pragma unroll
            for (int t = 0; t < 4; ++t) {
                const int p0 = t * 16 + kg * 4;
                float4 add;
                {
                    const int p = p0 + 0, rv = ((p & 7) << 3) | (p >> 3);
                    add.x = q2_s[row16 * QS + rv];
                }
                {
                    const int p = p0 + 1, rv = ((p & 7) << 3) | (p >> 3);
                    add.y = q2_s[row16 * QS + rv];
                }
                {
                    const int p = p0 + 2, rv = ((p & 7) << 3) | (p >> 3);
                    add.z = q2_s[row16 * QS + rv];
                }
                {
                    const int p = p0 + 3, rv = ((p & 7) << 3) | (p >> 3);
                    add.w = q2_s[row16 * QS + rv];
                }
                float4 res;
                res.x = g1[t][0] + add.x; res.y = g1[t][1] + add.y;
                res.z = g1[t][2] + add.z; res.w = g1[t][3] + add.w;
                *(float4*)&q_s[row16 * QS + p0] = res;
            }
        }

        // ---- phase 3: lane = ordered pair (a,bb), sweep cc for all 4 i ----
        float mn[4] = {INFINITY, INFINITY, INFINITY, INFINITY};
        if (lane < 56) {
            const int a  = lane / 7;
            const int o  = lane - a * 7;
            const int bb = o + (o >= a);
            #pragma unroll
            for (int i = 0; i < 4; ++i) {
                const float bs = q_s[(i * 3 + 0) * QS + a * 8 + bb]
                               + ss_s[(i * 3 + 0) * SS + a]
                               + ss_s[(i * 3 + 1) * SS + bb];
                const float4 c0 = *(const float4*)&q_s[(i * 3 + 1) * QS + a * 8];
                const float4 c1 = *(const float4*)&q_s[(i * 3 + 1) * QS + a * 8 + 4];
                const float4 d0 = *(const float4*)&q_s[(i * 3 + 2) * QS + bb * 8];
                const float4 d1 = *(const float4*)&q_s[(i * 3 + 2) * QS + bb * 8 + 4];
                const float4 e0 = *(const float4*)&ss_s[(i * 3 + 2) * SS];      // uniform
                const float4 e1 = *(const float4*)&ss_s[(i * 3 + 2) * SS + 4];  // broadcast
                float vv[8];
                vv[0] = c0.x + d0.x + e0.x; vv[1] = c0.y + d0.y + e0.y;
                vv[2] = c0.z + d0.z + e0.z; vv[3] = c0.w + d0.w + e0.w;
                vv[4] = c1.x + d1.x + e1.x; vv[5] = c1.y + d1.y + e1.y;
                vv[6] = c1.z + d1.z + e1.z; vv[7] = c1.w + d1.w + e1.w;
                float m = INFINITY;
                #pragma unroll
                for (int cc = 0; cc < 8; ++cc) {
                    const float s = (cc == a || cc == bb) ? INFINITY : (bs + vv[cc]);
                    m = fminf(m, s);
                }
                mn[i] = m;
            }
        }
        #pragma unroll
        for (int s = 1; s <= 32; s <<= 1) {
            #pragma unroll
            for (int i = 0; i < 4; ++i) mn[i] = fminf(mn[i], __shfl_xor(mn[i], s));
        }
        if (lane == 0) {
            const float mx = fmaxf(fmaxf(mn[0], mn[1]), fmaxf(mn[2], mn[3]));
            const float e0 = expf(mn[0] - mx), e1 = expf(mn[1] - mx);
            const float e2 = expf(mn[2] - mx), e3 = expf(mn[3] - mx);
            const float inv = 1.f / (e0 + e1 + e2 + e3);
            *(float4*)(out + (size_t)(b0 + e) * 4) =
                make_float4((e0 + e1) * inv, (e2 + e3) * inv, 0.f, 0.f);
        }

        // ---- LDS reuse guard between elements (WAR): wait DS only; keeps
        // elem1 global prefetch in flight. sched_barrier blocks hoisting. ----
        if (e == 0) {
            asm volatile("s_waitcnt lgkmcnt(0)" ::: "memory");
            __builtin_amdgcn_sched_barrier(0);
        }
    }
}

extern "C" void kernel_launch(void* const* d_in, const int* in_sizes, int n_in,
                              void* d_out, int out_size, void* d_ws, size_t ws_size,
                              hipStream_t stream) {
    const float* uf = (const float*)d_in[0];   // (4096,8,64)
    const float* bf = (const float*)d_in[1];   // (4096,8,8,64)
    const float* ru = (const float*)d_in[2];   // (4,3,64)
    const float* rb = (const float*)d_in[3];   // (4,3,3,64)
    float* out = (float*)d_out;                // (4096,4)

    const int B = in_sizes[0] / (8 * 64);      // 4096
    rule_learner_kernel<<<B / 2, 64, 0, stream>>>(uf, bf, ru, rb, out);
}